// Round 5
// baseline (350.450 us; speedup 1.0000x reference)
//
#include <hip/hip_runtime.h>

namespace {
constexpr int NB = 32;      // batch
constexpr int NN = 2000;    // nodes
constexpr int NE = 64000;   // edges
constexpr int ND = 128;     // feature dim
constexpr int NCHUNK = 63;  // ceil(2000/32) node tiles per batch
constexpr int NXCD = 8;
constexpr int BPX = NB / NXCD;            // batches per XCD = 4
constexpr int GRID_FUSED = NXCD * BPX * NCHUNK;  // 2016
constexpr int ECAP = 1536;  // LDS edge cap per 32-row tile (mean 1024, sigma~32)

// ---- workspace layout (bytes) ----
constexpr size_t OFF_DINV = 0;                            // float[2048]
constexpr size_t OFF_WSUM = OFF_DINV + 2048 * 4;          // float[2048]
constexpr size_t OFF_OFFS = OFF_WSUM + 2048 * 4;          // int[2052]
constexpr size_t OFF_CUR  = OFF_OFFS + 2052 * 4;          // int[2048]
constexpr size_t OFF_Y    = OFF_CUR  + 2048 * 4;          // float[4096]
constexpr size_t OFF_DONE = OFF_Y    + 4096 * 4;          // int[4]
constexpr size_t OFF_CSR  = OFF_DONE + 4 * 4;             // int2[NE]
} // namespace

// ---- S1: histogram (LDS) + dinv/wsum + scan -> offs + zero cur/y/done ----
__global__ __launch_bounds__(1024) void k_prep(const int* __restrict__ dst,
                                               float* __restrict__ dinv_g,
                                               float* __restrict__ wsum_g,
                                               int* __restrict__ offs_g,
                                               int* __restrict__ cur,
                                               float* __restrict__ y,
                                               int* __restrict__ done) {
    __shared__ int s[2048];
    const int t = threadIdx.x;
    s[t] = 0; s[t + 1024] = 0;
    __syncthreads();
    const int4* dst4 = (const int4*)dst;
    for (int e = t; e < NE / 4; e += 1024) {
        int4 d = dst4[e];
        atomicAdd(&s[d.x], 1); atomicAdd(&s[d.y], 1);
        atomicAdd(&s[d.z], 1); atomicAdd(&s[d.w], 1);
    }
    __syncthreads();
    int c0 = s[t], c1 = s[t + 1024];
    float d0 = rsqrtf((float)(c0 + 1));   // deg = in_degree + 1 (self loop)
    float d1 = rsqrtf((float)(c1 + 1));
    dinv_g[t] = d0;        dinv_g[t + 1024] = d1;
    wsum_g[t] = d0 * d0;   wsum_g[t + 1024] = d1 * d1;   // self-loop term
    ((float4*)y)[t] = make_float4(0.f, 0.f, 0.f, 0.f);   // 4096 floats
    cur[t] = 0; cur[t + 1024] = 0;
    if (t == 0) done[0] = 0;
    // Hillis-Steele inclusive scan (reads-before-barrier / writes-after pattern)
    for (int off = 1; off < 2048; off <<= 1) {
        int v0 = (t >= off) ? s[t - off] : 0;
        int v1 = (t + 1024 >= off) ? s[t + 1024 - off] : 0;
        __syncthreads();
        s[t] += v0;
        s[t + 1024] += v1;
        __syncthreads();
    }
    if (t == 0) offs_g[0] = 0;
    offs_g[t + 1]    = s[t];            // exclusive offsets; offs[n]=NE for n>=NN
    offs_g[t + 1025] = s[t + 1024];
}

// ---- S2: CSR fill + wsum out-edge terms, edge-parallel ----
__global__ void k_fill(const int* __restrict__ src, const int* __restrict__ dst,
                       const float* __restrict__ dinv, const int* __restrict__ offs,
                       int* __restrict__ cur, float* __restrict__ wsum,
                       int2* __restrict__ csr) {
    int e = blockIdx.x * 256 + threadIdx.x;
    if (e < NE / 4) {
        int4 s4 = ((const int4*)src)[e];
        int4 d4 = ((const int4*)dst)[e];
        int ss[4] = {s4.x, s4.y, s4.z, s4.w};
        int dd[4] = {d4.x, d4.y, d4.z, d4.w};
        #pragma unroll
        for (int q = 0; q < 4; q++) {
            float w = dinv[ss[q]] * dinv[dd[q]];
            atomicAdd(&wsum[ss[q]], w);
            int p = offs[dd[q]] + atomicAdd(&cur[dd[q]], 1);
            csr[p] = make_int2(ss[q], __float_as_int(w));
        }
    }
}

// ---- fused: LDS edge staging, high-MLP gather, GEMM, reduce, last-block out ----
__global__ __launch_bounds__(256) void k_fused(const float* __restrict__ X,
                                               const int* __restrict__ offs,
                                               const int2* __restrict__ csr,
                                               const float* __restrict__ dinv,
                                               const float* __restrict__ W1,
                                               const float* __restrict__ b1,
                                               const float* __restrict__ wsum,
                                               float* __restrict__ y,
                                               int* __restrict__ done,
                                               const float* __restrict__ W2,
                                               const float* __restrict__ b2,
                                               float* __restrict__ out) {
    __shared__ float4 As4[32 * 33];     // 16896 B, row stride 33 float4
    __shared__ int2   sEdge[ECAP];      // 12288 B
    __shared__ int    sOffs[33];
    __shared__ float  sDinv[32];
    __shared__ float  sWsum[32];
    __shared__ float  yred[128];
    __shared__ int    sTicket;
    const int tid = threadIdx.x;

    // XCD batch-partition swizzle: each XCD's L2 sees only its 4 batches (~4 MB X)
    const int L     = blockIdx.x;
    const int xcd   = L & (NXCD - 1);
    const int slot  = L >> 3;
    const int b     = xcd * BPX + slot / NCHUNK;
    const int chunk = slot % NCHUNK;
    const int n0    = chunk * 32;

    const float2* __restrict__ Xb2 = (const float2*)(X + (size_t)b * NN * ND); // row stride 64
    float2* As2 = (float2*)As4;     // row stride 66 float2s

    // stage per-tile metadata
    if (tid < 33) sOffs[tid] = offs[n0 + tid];                       // n0+32 <= 2016 < 2050
    else if (tid >= 64 && tid < 96)  sDinv[tid - 64] = dinv[n0 + tid - 64];
    else if (tid >= 96 && tid < 128) sWsum[tid - 96] = wsum[n0 + tid - 96];
    if (tid < 128) yred[tid] = 0.f;
    __syncthreads();
    const int eBase = sOffs[0];
    const int nEt   = sOffs[32] - eBase;
    const int nStage = min(nEt, ECAP);
    for (int i = tid; i < nStage; i += 256) sEdge[i] = csr[eBase + i];  // coalesced burst
    __syncthreads();

    // ---- gather: wave wv owns rows wv*8..+7; lane ln owns float2 slot; MLP=8 ----
    const int wv = tid >> 6, ln = tid & 63;
    #pragma unroll 1
    for (int i = 0; i < 8; i++) {
        const int j = wv * 8 + i;
        const int n = n0 + j;
        float2 a = make_float2(0.f, 0.f);
        if (n < NN) {                       // row-uniform branch
            float sn = sDinv[j]; sn *= sn;
            float2 x = Xb2[n * 64 + ln];
            a.x = sn * x.x; a.y = sn * x.y;
            const int e0 = sOffs[j] - eBase, e1 = sOffs[j + 1] - eBase;
            const int ec = min(e1, ECAP);
            int e = e0;
            for (; e + 8 <= ec; e += 8) {
                float w[8]; float2 xs[8];
                #pragma unroll
                for (int q = 0; q < 8; q++) {
                    int2 ed = sEdge[e + q];            // LDS broadcast
                    w[q]  = __int_as_float(ed.y);
                    xs[q] = Xb2[ed.x * 64 + ln];       // 8 independent 512B loads
                }
                #pragma unroll
                for (int q = 0; q < 8; q++) {
                    a.x = fmaf(w[q], xs[q].x, a.x);
                    a.y = fmaf(w[q], xs[q].y, a.y);
                }
            }
            for (; e < ec; e++) {
                int2 ed = sEdge[e];
                float w = __int_as_float(ed.y);
                float2 xs = Xb2[ed.x * 64 + ln];
                a.x = fmaf(w, xs.x, a.x); a.y = fmaf(w, xs.y, a.y);
            }
            for (; e < e1; e++) {                      // ECAP overflow fallback
                int2 ed = csr[eBase + e];
                float w = __int_as_float(ed.y);
                float2 xs = Xb2[ed.x * 64 + ln];
                a.x = fmaf(w, xs.x, a.x); a.y = fmaf(w, xs.y, a.y);
            }
        }
        As2[j * 66 + ln] = a;
    }
    __syncthreads();

    // ---- GEMM: thread (c=tid&31, rg=tid>>5) -> rows rg*4..+3, cols 4c..4c+3 ----
    const int c = tid & 31, rg = tid >> 5;
    float4 acc[4];
    #pragma unroll
    for (int i = 0; i < 4; i++) acc[i] = make_float4(0.f, 0.f, 0.f, 0.f);
    const float4* __restrict__ W4 = (const float4*)W1 + c;
    #pragma unroll 2
    for (int k4 = 0; k4 < 32; k4++) {
        float4 w0 = W4[(4 * k4 + 0) * 32];
        float4 w1 = W4[(4 * k4 + 1) * 32];
        float4 w2 = W4[(4 * k4 + 2) * 32];
        float4 w3 = W4[(4 * k4 + 3) * 32];
        #pragma unroll
        for (int i = 0; i < 4; i++) {
            float4 a = As4[(rg * 4 + i) * 33 + k4];   // 2-way broadcast read
            acc[i].x = fmaf(a.x, w0.x, acc[i].x);
            acc[i].x = fmaf(a.y, w1.x, acc[i].x);
            acc[i].x = fmaf(a.z, w2.x, acc[i].x);
            acc[i].x = fmaf(a.w, w3.x, acc[i].x);
            acc[i].y = fmaf(a.x, w0.y, acc[i].y);
            acc[i].y = fmaf(a.y, w1.y, acc[i].y);
            acc[i].y = fmaf(a.z, w2.y, acc[i].y);
            acc[i].y = fmaf(a.w, w3.y, acc[i].y);
            acc[i].z = fmaf(a.x, w0.z, acc[i].z);
            acc[i].z = fmaf(a.y, w1.z, acc[i].z);
            acc[i].z = fmaf(a.z, w2.z, acc[i].z);
            acc[i].z = fmaf(a.w, w3.z, acc[i].z);
            acc[i].w = fmaf(a.x, w0.w, acc[i].w);
            acc[i].w = fmaf(a.y, w1.w, acc[i].w);
            acc[i].w = fmaf(a.z, w2.w, acc[i].w);
            acc[i].w = fmaf(a.w, w3.w, acc[i].w);
        }
    }

    // ---- epilogue: relu + wsum-weighted reduce over this thread's 4 rows ----
    float4 bias = ((const float4*)b1)[c];
    float4 ya = make_float4(0.f, 0.f, 0.f, 0.f);
    #pragma unroll
    for (int i = 0; i < 4; i++) {
        int j = rg * 4 + i;
        if (n0 + j < NN) {
            float wn = sWsum[j];
            ya.x = fmaf(wn, fmaxf(acc[i].x + bias.x, 0.f), ya.x);
            ya.y = fmaf(wn, fmaxf(acc[i].y + bias.y, 0.f), ya.y);
            ya.z = fmaf(wn, fmaxf(acc[i].z + bias.z, 0.f), ya.z);
            ya.w = fmaf(wn, fmaxf(acc[i].w + bias.w, 0.f), ya.w);
        }
    }
    atomicAdd(&yred[4 * c + 0], ya.x);
    atomicAdd(&yred[4 * c + 1], ya.y);
    atomicAdd(&yred[4 * c + 2], ya.z);
    atomicAdd(&yred[4 * c + 3], ya.w);
    __syncthreads();
    if (tid < 128) atomicAdd(&y[b * ND + tid], yred[tid]);

    // ---- last-block ticket: compute out = (1/N) y @ W2 + b2 ----
    __threadfence();                      // release y updates device-wide
    __syncthreads();                      // all 256 threads' adds precede ticket
    if (tid == 0) sTicket = atomicAdd(done, 1);
    __syncthreads();
    if (sTicket == GRID_FUSED - 1) {
        float* ysh = (float*)As4;         // reuse As LDS as ys[4096]
        for (int i = tid; i < NB * ND; i += 256)
            ysh[i] = __hip_atomic_load(&y[i], __ATOMIC_RELAXED,
                                       __HIP_MEMORY_SCOPE_AGENT) * (1.f / (float)NN);
        __syncthreads();
        for (int o = tid; o < NB * ND; o += 256) {
            int bb = o >> 7, d = o & 127;
            float accO = b2[d];
            const float* yb = ysh + bb * 128;
            #pragma unroll 8
            for (int k = 0; k < 128; k++)
                accO = fmaf(yb[k], W2[k * ND + d], accO);
            out[o] = accO;
        }
    }
}

extern "C" void kernel_launch(void* const* d_in, const int* in_sizes, int n_in,
                              void* d_out, int out_size, void* d_ws, size_t ws_size,
                              hipStream_t stream) {
    (void)in_sizes; (void)n_in; (void)out_size; (void)ws_size;
    const float* X   = (const float*)d_in[0];
    const int*   src = (const int*)d_in[1];
    const int*   dst = (const int*)d_in[2];
    const float* W1  = (const float*)d_in[3];
    const float* b1  = (const float*)d_in[4];
    const float* W2  = (const float*)d_in[5];
    const float* b2  = (const float*)d_in[6];
    float* out = (float*)d_out;

    char* ws = (char*)d_ws;
    float* dinv = (float*)(ws + OFF_DINV);
    float* wsum = (float*)(ws + OFF_WSUM);
    int*   offs = (int*)  (ws + OFF_OFFS);
    int*   cur  = (int*)  (ws + OFF_CUR);
    float* y    = (float*)(ws + OFF_Y);
    int*   done = (int*)  (ws + OFF_DONE);
    int2*  csr  = (int2*) (ws + OFF_CSR);

    k_prep<<<1, 1024, 0, stream>>>(dst, dinv, wsum, offs, cur, y, done);
    k_fill<<<(NE / 4 + 255) / 256, 256, 0, stream>>>(src, dst, dinv, offs, cur, wsum, csr);
    k_fused<<<GRID_FUSED, 256, 0, stream>>>(X, offs, csr, dinv, W1, b1, wsum,
                                            y, done, W2, b2, out);
}

// Round 6
// 213.233 us; speedup vs baseline: 1.6435x; 1.6435x over previous
//
#include <hip/hip_runtime.h>

namespace {
constexpr int NB = 32;      // batch
constexpr int NN = 2000;    // nodes
constexpr int NE = 64000;   // edges
constexpr int ND = 128;     // feature dim
constexpr int NCHUNK = 63;  // ceil(2000/32) node tiles per batch
constexpr int NXCD = 8;
constexpr int BPX = NB / NXCD;            // batches per XCD = 4
constexpr int GRID_FUSED = NXCD * BPX * NCHUNK;  // 2016
constexpr int ECAP = 1536;  // LDS edge cap per 32-row tile (mean 1024)

// ---- workspace layout (bytes) ----
constexpr size_t OFF_DINV = 0;                            // float[2048]
constexpr size_t OFF_WSUM = OFF_DINV + 2048 * 4;          // float[2048]
constexpr size_t OFF_OFFS = OFF_WSUM + 2048 * 4;          // int[2052]
constexpr size_t OFF_CUR  = OFF_OFFS + 2052 * 4;          // int[2048]
constexpr size_t OFF_Y    = OFF_CUR  + 2048 * 4;          // float[4096]
constexpr size_t OFF_CSR  = OFF_Y    + 4096 * 4;          // int2[NE]
} // namespace

// ---- S1: histogram (LDS) + dinv/wsum + scan -> offs + zero cur/y ----
__global__ __launch_bounds__(1024) void k_prep(const int* __restrict__ dst,
                                               float* __restrict__ dinv_g,
                                               float* __restrict__ wsum_g,
                                               int* __restrict__ offs_g,
                                               int* __restrict__ cur,
                                               float* __restrict__ y) {
    __shared__ int s[2048];
    const int t = threadIdx.x;
    s[t] = 0; s[t + 1024] = 0;
    __syncthreads();
    const int4* dst4 = (const int4*)dst;
    for (int e = t; e < NE / 4; e += 1024) {
        int4 d = dst4[e];
        atomicAdd(&s[d.x], 1); atomicAdd(&s[d.y], 1);
        atomicAdd(&s[d.z], 1); atomicAdd(&s[d.w], 1);
    }
    __syncthreads();
    int c0 = s[t], c1 = s[t + 1024];
    float d0 = rsqrtf((float)(c0 + 1));   // deg = in_degree + 1 (self loop)
    float d1 = rsqrtf((float)(c1 + 1));
    dinv_g[t] = d0;        dinv_g[t + 1024] = d1;
    wsum_g[t] = d0 * d0;   wsum_g[t + 1024] = d1 * d1;   // self-loop term
    ((float4*)y)[t] = make_float4(0.f, 0.f, 0.f, 0.f);   // 4096 floats
    cur[t] = 0; cur[t + 1024] = 0;
    // Hillis-Steele inclusive scan
    for (int off = 1; off < 2048; off <<= 1) {
        int v0 = (t >= off) ? s[t - off] : 0;
        int v1 = (t + 1024 >= off) ? s[t + 1024 - off] : 0;
        __syncthreads();
        s[t] += v0;
        s[t + 1024] += v1;
        __syncthreads();
    }
    if (t == 0) offs_g[0] = 0;
    offs_g[t + 1]    = s[t];            // exclusive offsets; offs[n]=NE for n>=NN
    offs_g[t + 1025] = s[t + 1024];
}

// ---- S2: CSR fill + wsum out-edge terms, edge-parallel ----
__global__ void k_fill(const int* __restrict__ src, const int* __restrict__ dst,
                       const float* __restrict__ dinv, const int* __restrict__ offs,
                       int* __restrict__ cur, float* __restrict__ wsum,
                       int2* __restrict__ csr) {
    int e = blockIdx.x * 256 + threadIdx.x;
    if (e < NE / 4) {
        int4 s4 = ((const int4*)src)[e];
        int4 d4 = ((const int4*)dst)[e];
        int ss[4] = {s4.x, s4.y, s4.z, s4.w};
        int dd[4] = {d4.x, d4.y, d4.z, d4.w};
        #pragma unroll
        for (int q = 0; q < 4; q++) {
            float w = dinv[ss[q]] * dinv[dd[q]];
            atomicAdd(&wsum[ss[q]], w);
            int p = offs[dd[q]] + atomicAdd(&cur[dd[q]], 1);
            csr[p] = make_int2(ss[q], __float_as_int(w));
        }
    }
}

// ---- fused: LDS edge staging, high-MLP gather, GEMM, wsum-weighted reduce ----
__global__ __launch_bounds__(256) void k_fused(const float* __restrict__ X,
                                               const int* __restrict__ offs,
                                               const int2* __restrict__ csr,
                                               const float* __restrict__ dinv,
                                               const float* __restrict__ W1,
                                               const float* __restrict__ b1,
                                               const float* __restrict__ wsum,
                                               float* __restrict__ y) {
    __shared__ float4 As4[32 * 33];     // 16896 B, row stride 33 float4
    __shared__ int2   sEdge[ECAP];      // 12288 B
    __shared__ int    sOffs[33];
    __shared__ float  sDinv[32];
    __shared__ float  sWsum[32];
    __shared__ float  yred[128];
    const int tid = threadIdx.x;

    // XCD batch-partition swizzle: each XCD's L2 sees only its 4 batches (~4 MB X)
    const int L     = blockIdx.x;
    const int xcd   = L & (NXCD - 1);
    const int slot  = L >> 3;
    const int b     = xcd * BPX + slot / NCHUNK;
    const int chunk = slot % NCHUNK;
    const int n0    = chunk * 32;

    const float2* __restrict__ Xb2 = (const float2*)(X + (size_t)b * NN * ND); // row stride 64
    float2* As2 = (float2*)As4;     // row stride 66 float2s

    // stage per-tile metadata
    if (tid < 33) sOffs[tid] = offs[n0 + tid];
    else if (tid >= 64 && tid < 96)  sDinv[tid - 64] = dinv[n0 + tid - 64];
    else if (tid >= 96 && tid < 128) sWsum[tid - 96] = wsum[n0 + tid - 96];
    if (tid < 128) yred[tid] = 0.f;
    __syncthreads();
    const int eBase = sOffs[0];
    const int nEt   = sOffs[32] - eBase;
    const int nStage = min(nEt, ECAP);
    for (int i = tid; i < nStage; i += 256) sEdge[i] = csr[eBase + i];  // coalesced burst
    __syncthreads();

    // ---- gather: wave wv owns rows wv*8..+7; lane ln owns float2 slot; MLP=8 ----
    const int wv = tid >> 6, ln = tid & 63;
    #pragma unroll 1
    for (int i = 0; i < 8; i++) {
        const int j = wv * 8 + i;
        const int n = n0 + j;
        float2 a = make_float2(0.f, 0.f);
        if (n < NN) {                       // row-uniform branch
            float sn = sDinv[j]; sn *= sn;
            float2 x = Xb2[n * 64 + ln];
            a.x = sn * x.x; a.y = sn * x.y;
            const int e0 = sOffs[j] - eBase, e1 = sOffs[j + 1] - eBase;
            const int ec = min(e1, ECAP);
            int e = e0;
            for (; e + 8 <= ec; e += 8) {
                float w[8]; float2 xs[8];
                #pragma unroll
                for (int q = 0; q < 8; q++) {
                    int2 ed = sEdge[e + q];            // LDS broadcast
                    w[q]  = __int_as_float(ed.y);
                    xs[q] = Xb2[ed.x * 64 + ln];       // 8 independent 512B loads
                }
                #pragma unroll
                for (int q = 0; q < 8; q++) {
                    a.x = fmaf(w[q], xs[q].x, a.x);
                    a.y = fmaf(w[q], xs[q].y, a.y);
                }
            }
            for (; e < ec; e++) {
                int2 ed = sEdge[e];
                float w = __int_as_float(ed.y);
                float2 xs = Xb2[ed.x * 64 + ln];
                a.x = fmaf(w, xs.x, a.x); a.y = fmaf(w, xs.y, a.y);
            }
            for (; e < e1; e++) {                      // ECAP overflow fallback
                int2 ed = csr[eBase + e];
                float w = __int_as_float(ed.y);
                float2 xs = Xb2[ed.x * 64 + ln];
                a.x = fmaf(w, xs.x, a.x); a.y = fmaf(w, xs.y, a.y);
            }
        }
        As2[j * 66 + ln] = a;
    }
    __syncthreads();

    // ---- GEMM: thread (c=tid&31, rg=tid>>5) -> rows rg*4..+3, cols 4c..4c+3 ----
    const int c = tid & 31, rg = tid >> 5;
    float4 acc[4];
    #pragma unroll
    for (int i = 0; i < 4; i++) acc[i] = make_float4(0.f, 0.f, 0.f, 0.f);
    const float4* __restrict__ W4 = (const float4*)W1 + c;
    #pragma unroll 2
    for (int k4 = 0; k4 < 32; k4++) {
        float4 w0 = W4[(4 * k4 + 0) * 32];
        float4 w1 = W4[(4 * k4 + 1) * 32];
        float4 w2 = W4[(4 * k4 + 2) * 32];
        float4 w3 = W4[(4 * k4 + 3) * 32];
        #pragma unroll
        for (int i = 0; i < 4; i++) {
            float4 a = As4[(rg * 4 + i) * 33 + k4];   // 2-way broadcast read
            acc[i].x = fmaf(a.x, w0.x, acc[i].x);
            acc[i].x = fmaf(a.y, w1.x, acc[i].x);
            acc[i].x = fmaf(a.z, w2.x, acc[i].x);
            acc[i].x = fmaf(a.w, w3.x, acc[i].x);
            acc[i].y = fmaf(a.x, w0.y, acc[i].y);
            acc[i].y = fmaf(a.y, w1.y, acc[i].y);
            acc[i].y = fmaf(a.z, w2.y, acc[i].y);
            acc[i].y = fmaf(a.w, w3.y, acc[i].y);
            acc[i].z = fmaf(a.x, w0.z, acc[i].z);
            acc[i].z = fmaf(a.y, w1.z, acc[i].z);
            acc[i].z = fmaf(a.z, w2.z, acc[i].z);
            acc[i].z = fmaf(a.w, w3.z, acc[i].z);
            acc[i].w = fmaf(a.x, w0.w, acc[i].w);
            acc[i].w = fmaf(a.y, w1.w, acc[i].w);
            acc[i].w = fmaf(a.z, w2.w, acc[i].w);
            acc[i].w = fmaf(a.w, w3.w, acc[i].w);
        }
    }

    // ---- epilogue: relu + wsum-weighted reduce over this thread's 4 rows ----
    float4 bias = ((const float4*)b1)[c];
    float4 ya = make_float4(0.f, 0.f, 0.f, 0.f);
    #pragma unroll
    for (int i = 0; i < 4; i++) {
        int j = rg * 4 + i;
        if (n0 + j < NN) {
            float wn = sWsum[j];
            ya.x = fmaf(wn, fmaxf(acc[i].x + bias.x, 0.f), ya.x);
            ya.y = fmaf(wn, fmaxf(acc[i].y + bias.y, 0.f), ya.y);
            ya.z = fmaf(wn, fmaxf(acc[i].z + bias.z, 0.f), ya.z);
            ya.w = fmaf(wn, fmaxf(acc[i].w + bias.w, 0.f), ya.w);
        }
    }
    atomicAdd(&yred[4 * c + 0], ya.x);
    atomicAdd(&yred[4 * c + 1], ya.y);
    atomicAdd(&yred[4 * c + 2], ya.z);
    atomicAdd(&yred[4 * c + 3], ya.w);
    __syncthreads();
    if (tid < 128) atomicAdd(&y[b * ND + tid], yred[tid]);
}

// ---- out[b,:] = (1/N) * y[b,:] @ W2 + b2 ----
__global__ __launch_bounds__(128) void k_out(const float* __restrict__ y,
                                             const float* __restrict__ W2,
                                             const float* __restrict__ b2,
                                             float* __restrict__ out) {
    __shared__ float ys[128];
    const int b = blockIdx.x;
    const int d = threadIdx.x;
    ys[d] = y[b * ND + d] * (1.f / (float)NN);
    __syncthreads();
    float acc = b2[d];
    #pragma unroll 8
    for (int k = 0; k < 128; k++)
        acc = fmaf(ys[k], W2[k * ND + d], acc);
    out[b * ND + d] = acc;
}

extern "C" void kernel_launch(void* const* d_in, const int* in_sizes, int n_in,
                              void* d_out, int out_size, void* d_ws, size_t ws_size,
                              hipStream_t stream) {
    (void)in_sizes; (void)n_in; (void)out_size; (void)ws_size;
    const float* X   = (const float*)d_in[0];
    const int*   src = (const int*)d_in[1];
    const int*   dst = (const int*)d_in[2];
    const float* W1  = (const float*)d_in[3];
    const float* b1  = (const float*)d_in[4];
    const float* W2  = (const float*)d_in[5];
    const float* b2  = (const float*)d_in[6];
    float* out = (float*)d_out;

    char* ws = (char*)d_ws;
    float* dinv = (float*)(ws + OFF_DINV);
    float* wsum = (float*)(ws + OFF_WSUM);
    int*   offs = (int*)  (ws + OFF_OFFS);
    int*   cur  = (int*)  (ws + OFF_CUR);
    float* y    = (float*)(ws + OFF_Y);
    int2*  csr  = (int2*) (ws + OFF_CSR);

    k_prep<<<1, 1024, 0, stream>>>(dst, dinv, wsum, offs, cur, y);
    k_fill<<<(NE / 4 + 255) / 256, 256, 0, stream>>>(src, dst, dinv, offs, cur, wsum, csr);
    k_fused<<<GRID_FUSED, 256, 0, stream>>>(X, offs, csr, dinv, W1, b1, wsum, y);
    k_out<<<NB, 128, 0, stream>>>(y, W2, b2, out);
}